// Round 2
// baseline (56822.046 us; speedup 1.0000x reference)
//
#include <hip/hip_runtime.h>
#include <math.h>

// ---------------------------------------------------------------------------
// Seq2Seq forward. V=50000 E=H=512 Lin=400 Tout=100 B=64 Lmax=400.
// R7: decoder occupancy + ILP fix. rocprof R6: MfmaUtil 0.6%, VALU 2.8%,
// HBM 157 GB/s, occupancy 12% -> latency-bound. Changes:
//   (1) k_dec_persist grid 256 -> 512 blocks (2 blocks/CU, 8 waves/CU),
//       __launch_bounds__(256,2) to guarantee co-residency.
//   (2) Phase D: prefetch all 16 out_W fragments into registers before the
//       MFMA chain (16 loads in flight per wave vs ~1).
//   (3) Phase A/B q-split widened 4 -> 8 sub-blocks per batch row.
// Encoder (R5) unchanged; tackled next round with counters.
// ---------------------------------------------------------------------------

typedef __attribute__((ext_vector_type(8))) short bh8;   // 8 x bf16 = 4 VGPR
typedef __attribute__((ext_vector_type(4))) float fv4;

__device__ __forceinline__ float b2f(short u) {
    union { unsigned int i; float f; } c;
    c.i = ((unsigned int)(unsigned short)u) << 16;
    return c.f;
}
// round-to-nearest-even f32 -> bf16 bits
__device__ __forceinline__ short f2b(float f) {
    union { float f; unsigned int u; } c;
    c.f = f;
    unsigned int r = (c.u + 0x7fffu + ((c.u >> 16) & 1u)) >> 16;
    return (short)r;
}
// load 8 consecutive f32, convert to bf16x8 fragment
__device__ __forceinline__ bh8 ld8(const float* __restrict__ p) {
    bh8 r;
    #pragma unroll
    for (int j = 0; j < 8; ++j) r[j] = f2b(p[j]);
    return r;
}
__device__ __forceinline__ float sigmf(float x) { return 1.f / (1.f + expf(-x)); }

__device__ __forceinline__ fv4 mfma16(bh8 a, bh8 b, fv4 c) {
    return __builtin_amdgcn_mfma_f32_16x16x32_bf16(a, b, c, 0, 0, 0);
}

// Grid barrier: monotone counter, agent-scope acq_rel. All blocks co-resident.
__device__ __forceinline__ void gridbar(unsigned int* bar, unsigned int target) {
    __syncthreads();
    if (threadIdx.x == 0) {
        __hip_atomic_fetch_add(bar, 1u, __ATOMIC_ACQ_REL, __HIP_MEMORY_SCOPE_AGENT);
        while (__hip_atomic_load(bar, __ATOMIC_ACQUIRE, __HIP_MEMORY_SCOPE_AGENT) < target) {
            __builtin_amdgcn_s_sleep(2);
        }
    }
    __syncthreads();
}

// f32 -> bf16 bulk convert (n multiple of 4; grid = n/1024 blocks)
__global__ __launch_bounds__(256) void k_cvt(
    const float* __restrict__ s, short* __restrict__ d, int n)
{
    const int i = (blockIdx.x * 256 + threadIdx.x) * 4;
    if (i + 3 < n) {
        fv4 v = *(const fv4*)(s + i);
        short4 o;
        o.x = f2b(v[0]); o.y = f2b(v[1]); o.z = f2b(v[2]); o.w = f2b(v[3]);
        *(short4*)(d + i) = o;
    }
}

// ---------------------------------------------------------------------------
// Persistent encoder: all 400 GRU steps in one launch. 32 blocks x 256 thr.
// (unchanged from R5)
// ---------------------------------------------------------------------------
__global__ __launch_bounds__(256) void k_enc_persist(
    const float* __restrict__ emb, const int* __restrict__ input_t,
    const short* __restrict__ Wb,
    const float* __restrict__ Wih_f, const float* __restrict__ Whh_f,
    const float* __restrict__ bih, const float* __restrict__ bhh,
    float* __restrict__ h_f32, short* __restrict__ h_bf,
    float* __restrict__ enc0, unsigned int* __restrict__ bar)
{
    const int tid  = threadIdx.x;
    const int lane = tid & 63;
    const int wv   = tid >> 6;            // b-tile index 0..3
    const int n0   = blockIdx.x * 16;     // n-strip
    const int b0   = wv * 16;
    const int l15  = lane & 15;
    const int ko   = lane >> 4;
    const int koff = ko * 8;
    const int brow = b0 + l15;
    const int n    = n0 + l15;

    for (int i = blockIdx.x * 256 + tid; i < 64 * 512; i += 32 * 256) {
        h_f32[i] = 0.f; h_bf[i] = 0;
    }
    gridbar(bar, 32u);

    const bh8 *Wrb = nullptr, *Wzb = nullptr, *Wnb = nullptr;
    const bh8 *Urb = nullptr, *Uzb = nullptr, *Unb = nullptr;
    const float *Wrf = nullptr, *Wzf = nullptr, *Wnf = nullptr;
    const float *Urf = nullptr, *Uzf = nullptr, *Unf = nullptr;
    if (Wb) {
        Wrb = (const bh8*)(Wb + (long long)(n + 0)    * 512) + ko;
        Wzb = (const bh8*)(Wb + (long long)(n + 512)  * 512) + ko;
        Wnb = (const bh8*)(Wb + (long long)(n + 1024) * 512) + ko;
        Urb = (const bh8*)(Wb + (long long)(n + 1536) * 512) + ko;
        Uzb = (const bh8*)(Wb + (long long)(n + 2048) * 512) + ko;
        Unb = (const bh8*)(Wb + (long long)(n + 2560) * 512) + ko;
    } else {
        Wrf = Wih_f + (long long)(n + 0)    * 512 + koff;
        Wzf = Wih_f + (long long)(n + 512)  * 512 + koff;
        Wnf = Wih_f + (long long)(n + 1024) * 512 + koff;
        Urf = Whh_f + (long long)(n + 0)    * 512 + koff;
        Uzf = Whh_f + (long long)(n + 512)  * 512 + koff;
        Unf = Whh_f + (long long)(n + 1024) * 512 + koff;
    }
    const float bir = bih[n], biz = bih[n + 512], bin = bih[n + 1024];
    const float bhr = bhh[n], bhz = bhh[n + 512], bhn = bhh[n + 1024];

    for (int t = 0; t < 400; ++t) {
        const float* hi  = h_f32 + (t & 1) * 32768;
        const short* hib = h_bf  + (t & 1) * 32768;
        float* ho  = h_f32 + ((t + 1) & 1) * 32768;
        short* hob = h_bf  + ((t + 1) & 1) * 32768;

        const int tok = input_t[t * 64 + brow];
        const float* Ap = emb + (long long)tok * 512 + koff;
        const bh8*  Hp  = (const bh8*)(hib + (long long)brow * 512) + ko;

        fv4 air = {0.f, 0.f, 0.f, 0.f};
        fv4 aiz = air, ain = air, ahr = air, ahz = air, ahn = air;
        if (Wb) {
            #pragma unroll 4
            for (int kk = 0; kk < 16; ++kk) {
                const bh8 a = ld8(Ap + kk * 32);
                const bh8 h = Hp[kk * 4];
                air = mfma16(a, Wrb[kk * 4], air);
                aiz = mfma16(a, Wzb[kk * 4], aiz);
                ain = mfma16(a, Wnb[kk * 4], ain);
                ahr = mfma16(h, Urb[kk * 4], ahr);
                ahz = mfma16(h, Uzb[kk * 4], ahz);
                ahn = mfma16(h, Unb[kk * 4], ahn);
            }
        } else {
            #pragma unroll 4
            for (int kk = 0; kk < 16; ++kk) {
                const bh8 a = ld8(Ap + kk * 32);
                const bh8 h = Hp[kk * 4];
                air = mfma16(a, ld8(Wrf + kk * 32), air);
                aiz = mfma16(a, ld8(Wzf + kk * 32), aiz);
                ain = mfma16(a, ld8(Wnf + kk * 32), ain);
                ahr = mfma16(h, ld8(Urf + kk * 32), ahr);
                ahz = mfma16(h, ld8(Uzf + kk * 32), ahz);
                ahn = mfma16(h, ld8(Unf + kk * 32), ahn);
            }
        }
        #pragma unroll
        for (int r = 0; r < 4; ++r) {
            const int b = b0 + ko * 4 + r;
            const float rr = sigmf(air[r] + bir + ahr[r] + bhr);
            const float zz = sigmf(aiz[r] + biz + ahz[r] + bhz);
            const float nn = tanhf(ain[r] + bin + rr * (ahn[r] + bhn));
            const float hold = hi[b * 512 + n];
            const float hnew = (1.f - zz) * nn + zz * hold;
            ho[b * 512 + n] = hnew;
            hob[b * 512 + n] = f2b(hnew);
            if (t == 0) enc0[b * 512 + n] = hnew;
        }
        gridbar(bar, 32u * (t + 2));
    }
}

// ---------------------------------------------------------------------------
// Fused persistent decoder: 100 steps, one launch. 512 blocks x 256 threads
// (2 blocks/CU, 8 waves/CU). Block (r = bid>>3, q = bid&7).
// Phase A: stage [x|h] in LDS; fold loss-red of step t-1 (q==0 blocks);
//          attention scores (q-th 50 rows of 400). gridbar.
// Phase B: softmax over scores row -> a0; combine GEMV (q-th 64 of 512)
//          -> c_bf. gridbar.
// Phase C: GRU step (blocks 0..31). gridbar.
// Phase D: out GEMM + online-LSE partials, 782 chunks over 512 blocks,
//          out_W fragments PREFETCHED into registers (16 loads in flight).
//          gridbar.
// ---------------------------------------------------------------------------
struct SmAB { float sx[1024]; float red[256]; float red2[256]; };
struct SmD  { float sl[64][65]; };
union SMem { SmAB ab; SmD d; };

__device__ __forceinline__ void dec_lossred(
    const float* __restrict__ pm, const float* __restrict__ ps,
    const float* __restrict__ tlog, float* __restrict__ lacc,
    float* red, float* red2, int r, int tid)
{
    float m = -1e30f, s = 0.f;
    for (int i = tid; i < 782; i += 256) {
        const float m2 = pm[i * 64 + r];
        const float s2 = ps[i * 64 + r];
        if (m2 > m) { s = s * expf(m - m2) + s2; m = m2; }
        else        { s += s2 * expf(m2 - m); }
    }
    red[tid] = m; red2[tid] = s;
    __syncthreads();
    for (int st = 128; st > 0; st >>= 1) {
        if (tid < st) {
            const float m2 = red[tid + st], s2 = red2[tid + st];
            const float M = fmaxf(red[tid], m2);
            red2[tid] = red2[tid] * expf(red[tid] - M) + s2 * expf(m2 - M);
            red[tid] = M;
        }
        __syncthreads();
    }
    if (tid == 0) {
        const float logp = tlog[r] - (red[0] + logf(red2[0]));
        atomicAdd(lacc, -logp * (1.f / 64.f));
    }
    __syncthreads();
}

__global__ __launch_bounds__(256, 2) void k_dec_persist(
    const float* __restrict__ emb, const float* __restrict__ enc0,
    const float* __restrict__ attn_W, const float* __restrict__ attn_b,
    const float* __restrict__ comb_W, const float* __restrict__ comb_b,
    const short* __restrict__ decWb,
    const float* __restrict__ dec_Wih, const float* __restrict__ dec_Whh,
    const float* __restrict__ dec_bih, const float* __restrict__ dec_bhh,
    const short* __restrict__ outWb, const float* __restrict__ outW,
    const float* __restrict__ outb, const int* __restrict__ target,
    float* __restrict__ h_f32, short* __restrict__ h_bf,
    short* __restrict__ c_bf, float* __restrict__ scores,
    float* __restrict__ pm, float* __restrict__ ps,
    float* __restrict__ tlog, float* __restrict__ lacc,
    unsigned int* __restrict__ bar2)
{
    __shared__ SMem sm;
    const int tid = threadIdx.x;
    const int bid = blockIdx.x;
    const int r   = bid >> 3;     // batch row 0..63
    const int q   = bid & 7;      // eighth
    unsigned int tgt = 0u;

    for (int t = 0; t < 100; ++t) {
        const float* hi  = h_f32 + (t & 1) * 32768;
        const short* hib = h_bf  + (t & 1) * 32768;
        float* ho  = h_f32 + ((t + 1) & 1) * 32768;
        short* hob = h_bf  + ((t + 1) & 1) * 32768;

        // ------------------ Phase A ------------------
        const int tok = (t == 0) ? 1 : target[(t - 1) * 64 + r];
        for (int k = tid; k < 512; k += 256) {
            sm.ab.sx[k]       = emb[(long long)tok * 512 + k];
            sm.ab.sx[512 + k] = hi[r * 512 + k];
        }
        if (q == 0 && t > 0)   // finish loss of step t-1 (disjoint LDS region)
            dec_lossred(pm, ps, tlog, lacc, sm.ab.red, sm.ab.red2, r, tid);
        __syncthreads();
        if (tid < 50) {
            const int nn = q * 50 + tid;
            const fv4* wrow = (const fv4*)(attn_W + (long long)nn * 1024);
            float s0 = 0.f, s1 = 0.f, s2 = 0.f, s3 = 0.f;
            for (int kc = 0; kc < 256; ++kc) {
                fv4 v = wrow[kc];
                s0 += v[0] * sm.ab.sx[kc * 4 + 0];
                s1 += v[1] * sm.ab.sx[kc * 4 + 1];
                s2 += v[2] * sm.ab.sx[kc * 4 + 2];
                s3 += v[3] * sm.ab.sx[kc * 4 + 3];
            }
            scores[r * 400 + nn] = (s0 + s1) + (s2 + s3) + attn_b[nn];
        }
        tgt += 512u; gridbar(bar2, tgt);

        // ------------------ Phase B ------------------
        {
            float m = -1e30f;
            for (int i = tid; i < 400; i += 256) m = fmaxf(m, scores[r * 400 + i]);
            sm.ab.red[tid] = m;
            __syncthreads();
            for (int st = 128; st > 0; st >>= 1) {
                if (tid < st) sm.ab.red[tid] = fmaxf(sm.ab.red[tid], sm.ab.red[tid + st]);
                __syncthreads();
            }
            m = sm.ab.red[0];
            __syncthreads();
            float ssum = 0.f;
            for (int i = tid; i < 400; i += 256) ssum += expf(scores[r * 400 + i] - m);
            sm.ab.red2[tid] = ssum;
            __syncthreads();
            for (int st = 128; st > 0; st >>= 1) {
                if (tid < st) sm.ab.red2[tid] += sm.ab.red2[tid + st];
                __syncthreads();
            }
            const float a0 = expf(scores[r * 400 + 0] - m) / sm.ab.red2[0];
            __syncthreads();
            for (int k = tid; k < 512; k += 256)
                sm.ab.sx[512 + k] = enc0[r * 512 + k] * a0;
            __syncthreads();
        }
        if (tid < 64) {
            const int j = q * 64 + tid;
            const fv4* wrow = (const fv4*)(comb_W + (long long)j * 1024);
            float s0 = 0.f, s1 = 0.f, s2 = 0.f, s3 = 0.f;
            for (int kc = 0; kc < 256; ++kc) {
                fv4 v = wrow[kc];
                s0 += v[0] * sm.ab.sx[kc * 4 + 0];
                s1 += v[1] * sm.ab.sx[kc * 4 + 1];
                s2 += v[2] * sm.ab.sx[kc * 4 + 2];
                s3 += v[3] * sm.ab.sx[kc * 4 + 3];
            }
            const float acc = (s0 + s1) + (s2 + s3) + comb_b[j];
            c_bf[r * 512 + j] = f2b(fmaxf(acc, 0.f));
        }
        tgt += 512u; gridbar(bar2, tgt);

        // ------------------ Phase C: GRU (blocks 0..31) ------------------
        if (bid < 32) {
            const int lane = tid & 63;
            const int w    = bid * 4 + (tid >> 6);
            const int b0g  = (w & 3) * 16;
            const int n0g  = (w >> 2) * 16;
            const int l15  = lane & 15;
            const int ko   = lane >> 4;
            const int koff = ko * 8;
            const int brow = b0g + l15;
            const int n    = n0g + l15;

            const bh8* Ap = (const bh8*)(c_bf + (long long)brow * 512) + ko;
            const bh8* Hp = (const bh8*)(hib + (long long)brow * 512) + ko;

            fv4 air = {0.f, 0.f, 0.f, 0.f};
            fv4 aiz = air, ain = air, ahr = air, ahz = air, ahn = air;
            if (decWb) {
                const bh8* Wr = (const bh8*)(decWb + (long long)(n + 0)    * 512) + ko;
                const bh8* Wz = (const bh8*)(decWb + (long long)(n + 512)  * 512) + ko;
                const bh8* Wn = (const bh8*)(decWb + (long long)(n + 1024) * 512) + ko;
                const bh8* Ur = (const bh8*)(decWb + (long long)(n + 1536) * 512) + ko;
                const bh8* Uz = (const bh8*)(decWb + (long long)(n + 2048) * 512) + ko;
                const bh8* Un = (const bh8*)(decWb + (long long)(n + 2560) * 512) + ko;
                #pragma unroll 4
                for (int kk = 0; kk < 16; ++kk) {
                    const bh8 a = Ap[kk * 4];
                    const bh8 h = Hp[kk * 4];
                    air = mfma16(a, Wr[kk * 4], air);
                    aiz = mfma16(a, Wz[kk * 4], aiz);
                    ain = mfma16(a, Wn[kk * 4], ain);
                    ahr = mfma16(h, Ur[kk * 4], ahr);
                    ahz = mfma16(h, Uz[kk * 4], ahz);
                    ahn = mfma16(h, Un[kk * 4], ahn);
                }
            } else {
                const float* Wr = dec_Wih + (long long)(n + 0)    * 512 + koff;
                const float* Wz = dec_Wih + (long long)(n + 512)  * 512 + koff;
                const float* Wn = dec_Wih + (long long)(n + 1024) * 512 + koff;
                const float* Ur = dec_Whh + (long long)(n + 0)    * 512 + koff;
                const float* Uz = dec_Whh + (long long)(n + 512)  * 512 + koff;
                const float* Un = dec_Whh + (long long)(n + 1024) * 512 + koff;
                #pragma unroll 4
                for (int kk = 0; kk < 16; ++kk) {
                    const bh8 a = Ap[kk * 4];
                    const bh8 h = Hp[kk * 4];
                    air = mfma16(a, ld8(Wr + kk * 32), air);
                    aiz = mfma16(a, ld8(Wz + kk * 32), aiz);
                    ain = mfma16(a, ld8(Wn + kk * 32), ain);
                    ahr = mfma16(h, ld8(Ur + kk * 32), ahr);
                    ahz = mfma16(h, ld8(Uz + kk * 32), ahz);
                    ahn = mfma16(h, ld8(Un + kk * 32), ahn);
                }
            }
            const float bir = dec_bih[n], biz = dec_bih[n + 512], bin = dec_bih[n + 1024];
            const float bhr = dec_bhh[n], bhz = dec_bhh[n + 512], bhn = dec_bhh[n + 1024];
            #pragma unroll
            for (int rr = 0; rr < 4; ++rr) {
                const int b = b0g + ko * 4 + rr;
                const float rg = sigmf(air[rr] + bir + ahr[rr] + bhr);
                const float zg = sigmf(aiz[rr] + biz + ahz[rr] + bhz);
                const float ng = tanhf(ain[rr] + bin + rg * (ahn[rr] + bhn));
                const float hold = hi[b * 512 + n];
                const float hnew = (1.f - zg) * ng + zg * hold;
                ho[b * 512 + n] = hnew;
                hob[b * 512 + n] = f2b(hnew);
            }
        }
        tgt += 512u; gridbar(bar2, tgt);

        // ------------------ Phase D: out GEMM + LSE partials ------------------
        for (int ch = bid; ch < 782; ch += 512) {
            const int lane = tid & 63;
            const int wl   = tid >> 6;
            const int base = ch * 64;
            const int n0c  = base + wl * 16;
            const int l15  = lane & 15;
            const int ko   = lane >> 4;
            const int v    = n0c + l15;
            const int vcl  = (v < 50000) ? v : 49999;
            const bh8* A0 = (const bh8*)(hob + (long long)(0  + l15) * 512) + ko;
            const bh8* A1 = (const bh8*)(hob + (long long)(16 + l15) * 512) + ko;
            const bh8* A2 = (const bh8*)(hob + (long long)(32 + l15) * 512) + ko;
            const bh8* A3 = (const bh8*)(hob + (long long)(48 + l15) * 512) + ko;

            // Prefetch the full out_W panel for this chunk: 16 independent
            // 16B loads in flight per wave (vs ~1 in R6's fused loop).
            bh8 bb[16];
            if (outWb) {
                const bh8* Bp = (const bh8*)(outWb + (long long)vcl * 512) + ko;
                #pragma unroll
                for (int kk = 0; kk < 16; ++kk) bb[kk] = Bp[kk * 4];
            } else {
                const float* Bp = outW + (long long)vcl * 512 + ko * 8;
                #pragma unroll
                for (int kk = 0; kk < 16; ++kk) bb[kk] = ld8(Bp + kk * 32);
            }
            fv4 c0 = {0.f, 0.f, 0.f, 0.f};
            fv4 c1 = c0, c2 = c0, c3 = c0;
            #pragma unroll
            for (int kk = 0; kk < 16; ++kk) {
                c0 = mfma16(A0[kk * 4], bb[kk], c0);
                c1 = mfma16(A1[kk * 4], bb[kk], c1);
                c2 = mfma16(A2[kk * 4], bb[kk], c2);
                c3 = mfma16(A3[kk * 4], bb[kk], c3);
            }
            const float bv = outb[vcl];
            const int cc = wl * 16 + l15;
            const bool ok = (v < 50000);
            #pragma unroll
            for (int rr = 0; rr < 4; ++rr) {
                const int row = ko * 4 + rr;
                sm.d.sl[0  + row][cc] = ok ? (c0[rr] + bv) : -1e30f;
                sm.d.sl[16 + row][cc] = ok ? (c1[rr] + bv) : -1e30f;
                sm.d.sl[32 + row][cc] = ok ? (c2[rr] + bv) : -1e30f;
                sm.d.sl[48 + row][cc] = ok ? (c3[rr] + bv) : -1e30f;
            }
            __syncthreads();
            if (tid < 64) {
                const int b = tid;
                float m = -1e30f, s = 0.f;
                for (int cj = 0; cj < 64; ++cj) {
                    const float x = sm.d.sl[b][cj];
                    if (x > m) { s = s * expf(m - x) + 1.f; m = x; }
                    else       { s += expf(x - m); }
                }
                pm[ch * 64 + b] = m;
                ps[ch * 64 + b] = s;
                const int tg = target[t * 64 + b];
                const int rel = tg - base;
                if (rel >= 0 && rel < 64) tlog[b] = sm.d.sl[b][rel];
            }
            __syncthreads();
        }
        tgt += 512u; gridbar(bar2, tgt);
    }

    // finish loss of step 99
    if (q == 0)
        dec_lossred(pm, ps, tlog, lacc, sm.ab.red, sm.ab.red2, r, tid);
}

// ---------------------------------------------------------------------------
// Fallback decoder kernels (used only when workspace is too small to fuse).
// ---------------------------------------------------------------------------
__global__ __launch_bounds__(256) void k_gru1(
    const short* __restrict__ c_bf, const short* __restrict__ Wb,
    const float* __restrict__ Wih_f, const float* __restrict__ Whh_f,
    const float* __restrict__ bih, const float* __restrict__ bhh,
    const float* __restrict__ hi, const short* __restrict__ hib,
    float* __restrict__ ho, short* __restrict__ hob)
{
    const int tid  = threadIdx.x;
    const int lane = tid & 63;
    const int w    = blockIdx.x * 4 + (tid >> 6);
    const int b0   = (w & 3) * 16;
    const int n0   = (w >> 2) * 16;
    const int l15  = lane & 15;
    const int ko   = lane >> 4;
    const int koff = ko * 8;
    const int brow = b0 + l15;
    const int n    = n0 + l15;

    const bh8* Ap = (const bh8*)(c_bf + (long long)brow * 512) + ko;
    const bh8* Hp = (const bh8*)(hib + (long long)brow * 512) + ko;

    fv4 air = {0.f, 0.f, 0.f, 0.f};
    fv4 aiz = air, ain = air, ahr = air, ahz = air, ahn = air;
    if (Wb) {
        const bh8* Wr = (const bh8*)(Wb + (long long)(n + 0)    * 512) + ko;
        const bh8* Wz = (const bh8*)(Wb + (long long)(n + 512)  * 512) + ko;
        const bh8* Wn = (const bh8*)(Wb + (long long)(n + 1024) * 512) + ko;
        const bh8* Ur = (const bh8*)(Wb + (long long)(n + 1536) * 512) + ko;
        const bh8* Uz = (const bh8*)(Wb + (long long)(n + 2048) * 512) + ko;
        const bh8* Un = (const bh8*)(Wb + (long long)(n + 2560) * 512) + ko;
        #pragma unroll 4
        for (int kk = 0; kk < 16; ++kk) {
            const bh8 a = Ap[kk * 4];
            const bh8 h = Hp[kk * 4];
            air = mfma16(a, Wr[kk * 4], air);
            aiz = mfma16(a, Wz[kk * 4], aiz);
            ain = mfma16(a, Wn[kk * 4], ain);
            ahr = mfma16(h, Ur[kk * 4], ahr);
            ahz = mfma16(h, Uz[kk * 4], ahz);
            ahn = mfma16(h, Un[kk * 4], ahn);
        }
    } else {
        const float* Wr = Wih_f + (long long)(n + 0)    * 512 + koff;
        const float* Wz = Wih_f + (long long)(n + 512)  * 512 + koff;
        const float* Wn = Wih_f + (long long)(n + 1024) * 512 + koff;
        const float* Ur = Whh_f + (long long)(n + 0)    * 512 + koff;
        const float* Uz = Whh_f + (long long)(n + 512)  * 512 + koff;
        const float* Un = Whh_f + (long long)(n + 1024) * 512 + koff;
        #pragma unroll 4
        for (int kk = 0; kk < 16; ++kk) {
            const bh8 a = Ap[kk * 4];
            const bh8 h = Hp[kk * 4];
            air = mfma16(a, ld8(Wr + kk * 32), air);
            aiz = mfma16(a, ld8(Wz + kk * 32), aiz);
            ain = mfma16(a, ld8(Wn + kk * 32), ain);
            ahr = mfma16(h, ld8(Ur + kk * 32), ahr);
            ahz = mfma16(h, ld8(Uz + kk * 32), ahz);
            ahn = mfma16(h, ld8(Un + kk * 32), ahn);
        }
    }
    const float bir = bih[n], biz = bih[n + 512], bin = bih[n + 1024];
    const float bhr = bhh[n], bhz = bhh[n + 512], bhn = bhh[n + 1024];
    #pragma unroll
    for (int r = 0; r < 4; ++r) {
        const int b = b0 + ko * 4 + r;
        const float rr = sigmf(air[r] + bir + ahr[r] + bhr);
        const float zz = sigmf(aiz[r] + biz + ahz[r] + bhz);
        const float nn = tanhf(ain[r] + bin + rr * (ahn[r] + bhn));
        const float hold = hi[b * 512 + n];
        const float hnew = (1.f - zz) * nn + zz * hold;
        ho[b * 512 + n] = hnew;
        hob[b * 512 + n] = f2b(hnew);
    }
}

__global__ __launch_bounds__(256) void k_attncomb(
    const float* __restrict__ emb, const float* __restrict__ h_f32,
    const float* __restrict__ enc0,
    const float* __restrict__ attn_W, const float* __restrict__ attn_b,
    const float* __restrict__ comb_W, const float* __restrict__ comb_b,
    const int* __restrict__ target, int td, short* __restrict__ c_bf)
{
    __shared__ float sx[1024];
    __shared__ float sc[400];
    __shared__ float red[256];
    __shared__ float a0s;
    const int b = blockIdx.x;
    const int tid = threadIdx.x;
    const int tok = (td == 0) ? 1 : target[(td - 1) * 64 + b];
    for (int k = tid; k < 512; k += 256) {
        sx[k] = emb[(long long)tok * 512 + k];
        sx[512 + k] = h_f32[b * 512 + k];
    }
    __syncthreads();
    for (int nn = tid; nn < 400; nn += 256) {
        const fv4* wrow = (const fv4*)(attn_W + (long long)nn * 1024);
        float acc = 0.f;
        for (int kc = 0; kc < 256; ++kc) {
            fv4 v = wrow[kc];
            acc += v[0] * sx[kc * 4 + 0] + v[1] * sx[kc * 4 + 1]
                 + v[2] * sx[kc * 4 + 2] + v[3] * sx[kc * 4 + 3];
        }
        sc[nn] = acc + attn_b[nn];
    }
    __syncthreads();
    float m = -1e30f;
    for (int nn = tid; nn < 400; nn += 256) m = fmaxf(m, sc[nn]);
    red[tid] = m;
    __syncthreads();
    for (int s = 128; s > 0; s >>= 1) {
        if (tid < s) red[tid] = fmaxf(red[tid], red[tid + s]);
        __syncthreads();
    }
    m = red[0];
    __syncthreads();
    float ss = 0.f;
    for (int nn = tid; nn < 400; nn += 256) ss += expf(sc[nn] - m);
    red[tid] = ss;
    __syncthreads();
    for (int s = 128; s > 0; s >>= 1) {
        if (tid < s) red[tid] += red[tid + s];
        __syncthreads();
    }
    if (tid == 0) a0s = expf(sc[0] - m) / red[0];
    __syncthreads();
    const float a0b = a0s;
    for (int k = tid; k < 512; k += 256) sx[512 + k] = enc0[b * 512 + k] * a0b;
    __syncthreads();
    for (int j = tid; j < 512; j += 256) {
        const fv4* wrow = (const fv4*)(comb_W + (long long)j * 1024);
        float acc = 0.f;
        for (int kc = 0; kc < 256; ++kc) {
            fv4 v = wrow[kc];
            acc += v[0] * sx[kc * 4 + 0] + v[1] * sx[kc * 4 + 1]
                 + v[2] * sx[kc * 4 + 2] + v[3] * sx[kc * 4 + 3];
        }
        acc += comb_b[j];
        c_bf[b * 512 + j] = f2b(fmaxf(acc, 0.f));
    }
}

__global__ __launch_bounds__(256) void k_outloss(
    const short* __restrict__ h2bf,
    const short* __restrict__ outWb, const float* __restrict__ outW,
    const float* __restrict__ outb, const int* __restrict__ target,
    float* __restrict__ pm, float* __restrict__ ps, float* __restrict__ tlogit)
{
    __shared__ float sl[64][65];
    const int tid  = threadIdx.x;
    const int lane = tid & 63;
    const int wl   = tid >> 6;
    const int base = blockIdx.x * 64;
    const int n0   = base + wl * 16;
    const int l15  = lane & 15;
    const int ko   = lane >> 4;

    const int v    = n0 + l15;
    const int vcl  = (v < 50000) ? v : 49999;
    const bh8* A0 = (const bh8*)(h2bf + (long long)(0  + l15) * 512) + ko;
    const bh8* A1 = (const bh8*)(h2bf + (long long)(16 + l15) * 512) + ko;
    const bh8* A2 = (const bh8*)(h2bf + (long long)(32 + l15) * 512) + ko;
    const bh8* A3 = (const bh8*)(h2bf + (long long)(48 + l15) * 512) + ko;
    fv4 c0 = {0.f, 0.f, 0.f, 0.f};
    fv4 c1 = c0, c2 = c0, c3 = c0;
    if (outWb) {
        const bh8* Bp = (const bh8*)(outWb + (long long)vcl * 512) + ko;
        #pragma unroll 4
        for (int kk = 0; kk < 16; ++kk) {
            const bh8 bb = Bp[kk * 4];
            c0 = mfma16(A0[kk * 4], bb, c0);
            c1 = mfma16(A1[kk * 4], bb, c1);
            c2 = mfma16(A2[kk * 4], bb, c2);
            c3 = mfma16(A3[kk * 4], bb, c3);
        }
    } else {
        const float* Bp = outW + (long long)vcl * 512 + ko * 8;
        #pragma unroll 4
        for (int kk = 0; kk < 16; ++kk) {
            const bh8 bb = ld8(Bp + kk * 32);
            c0 = mfma16(A0[kk * 4], bb, c0);
            c1 = mfma16(A1[kk * 4], bb, c1);
            c2 = mfma16(A2[kk * 4], bb, c2);
            c3 = mfma16(A3[kk * 4], bb, c3);
        }
    }
    const float bv = outb[vcl];
    const int cc = wl * 16 + l15;
    const bool ok = (v < 50000);
    #pragma unroll
    for (int r = 0; r < 4; ++r) {
        const int row = ko * 4 + r;
        sl[0  + row][cc] = ok ? (c0[r] + bv) : -1e30f;
        sl[16 + row][cc] = ok ? (c1[r] + bv) : -1e30f;
        sl[32 + row][cc] = ok ? (c2[r] + bv) : -1e30f;
        sl[48 + row][cc] = ok ? (c3[r] + bv) : -1e30f;
    }
    __syncthreads();
    if (tid < 64) {
        const int b = tid;
        float m = -1e30f, s = 0.f;
        for (int c = 0; c < 64; ++c) {
            const float x = sl[b][c];
            if (x > m) { s = s * expf(m - x) + 1.f; m = x; }
            else       { s += expf(x - m); }
        }
        pm[blockIdx.x * 64 + b] = m;
        ps[blockIdx.x * 64 + b] = s;
        const int tg = target[b];
        const int rel = tg - base;
        if (rel >= 0 && rel < 64) tlogit[b] = sl[b][rel];
    }
}

__global__ __launch_bounds__(256) void k_lossred(
    const float* __restrict__ pm, const float* __restrict__ ps,
    const float* __restrict__ tlogit, float* __restrict__ loss_acc)
{
    __shared__ float rm[256], rs[256];
    const int b = blockIdx.x;
    const int tid = threadIdx.x;
    float m = -1e30f, s = 0.f;
    for (int i = tid; i < 782; i += 256) {
        const float m2 = pm[i * 64 + b];
        const float s2 = ps[i * 64 + b];
        if (m2 > m) { s = s * expf(m - m2) + s2; m = m2; }
        else        { s += s2 * expf(m2 - m); }
    }
    rm[tid] = m; rs[tid] = s;
    __syncthreads();
    for (int st = 128; st > 0; st >>= 1) {
        if (tid < st) {
            const float m2 = rm[tid + st], s2 = rs[tid + st];
            const float M = fmaxf(rm[tid], m2);
            rs[tid] = rs[tid] * expf(rm[tid] - M) + s2 * expf(m2 - M);
            rm[tid] = M;
        }
        __syncthreads();
    }
    if (tid == 0) {
        const float logp = tlogit[b] - (rm[0] + logf(rs[0]));
        atomicAdd(loss_acc, -logp * (1.f / 64.f));
    }
}

__global__ void k_init(float* h_f32_0, short* h_bf_0, float* loss_acc,
                       unsigned int* bar, unsigned int* bar2)
{
    const int i = blockIdx.x * 256 + threadIdx.x;
    if (i < 64 * 512) { h_f32_0[i] = 0.f; h_bf_0[i] = 0; }
    if (i == 0) { *loss_acc = 0.f; *bar = 0u; *bar2 = 0u; }
}

__global__ void k_final(const float* loss_acc, float* out)
{
    out[0] = *loss_acc;
}

extern "C" void kernel_launch(void* const* d_in, const int* in_sizes, int n_in,
                              void* d_out, int out_size, void* d_ws, size_t ws_size,
                              hipStream_t stream)
{
    const float* emb     = (const float*)d_in[0];
    const float* enc_Wih = (const float*)d_in[1];
    const float* enc_Whh = (const float*)d_in[2];
    const float* enc_bih = (const float*)d_in[3];
    const float* enc_bhh = (const float*)d_in[4];
    const float* attn_W  = (const float*)d_in[5];
    const float* attn_b  = (const float*)d_in[6];
    const float* comb_W  = (const float*)d_in[7];
    const float* comb_b  = (const float*)d_in[8];
    const float* dec_Wih = (const float*)d_in[9];
    const float* dec_Whh = (const float*)d_in[10];
    const float* dec_bih = (const float*)d_in[11];
    const float* dec_bhh = (const float*)d_in[12];
    const float* out_W   = (const float*)d_in[13];
    const float* out_b   = (const float*)d_in[14];
    const int*   input_t = (const int*)d_in[15];
    const int*   target_t= (const int*)d_in[16];

    char* ws = (char*)d_ws;
    float* h_f32  = (float*)(ws + 0);          // 2 x [64,512] f32
    float* enc0   = (float*)(ws + 262144);
    short* h_bf   = (short*)(ws + 393216);     // 2 x [64,512] bf16
    short* c_bf   = (short*)(ws + 524288);
    float* lacc   = (float*)(ws + 589824);
    unsigned int* bar  = (unsigned int*)(ws + 590080);
    unsigned int* bar2 = (unsigned int*)(ws + 590208);
    float* pm     = (float*)(ws + 590336);     // [782,64]
    float* ps     = (float*)(ws + 790528);
    float* tlog   = (float*)(ws + 990720);
    short* encWb  = (short*)(ws + 990976);     // 3072x512 bf16 = 3145728 B
    float* scores = (float*)(ws + 990976);     // [64,400] f32 aliases encWb
                                               // (encoder dead when decoder runs)
    short* decWb  = (short*)(ws + 4136704);    // 3145728 B
    short* outWb  = (short*)(ws + 7282432);    // 25600000 bf16 = 51200000 B

    const bool tier1 = ws_size >= 7282432;     // enc/dec weights bf16
    const bool tier2 = ws_size >= 58482432;    // + out_W bf16
    const bool fuse  = ws_size >= 1093376;     // scores region present

    k_init<<<128, 256, 0, stream>>>(h_f32, h_bf, lacc, bar, bar2);

    if (tier1) {
        k_cvt<<<768, 256, 0, stream>>>(enc_Wih, encWb, 786432);
        k_cvt<<<768, 256, 0, stream>>>(enc_Whh, encWb + 786432, 786432);
        k_cvt<<<768, 256, 0, stream>>>(dec_Wih, decWb, 786432);
        k_cvt<<<768, 256, 0, stream>>>(dec_Whh, decWb + 786432, 786432);
    }
    if (tier2) {
        k_cvt<<<25000, 256, 0, stream>>>(out_W, outWb, 25600000);
    }

    // ---- encoder: one persistent launch, 400 steps, grid barrier ----
    k_enc_persist<<<32, 256, 0, stream>>>(
        emb, input_t, tier1 ? encWb : nullptr, enc_Wih, enc_Whh,
        enc_bih, enc_bhh, h_f32, h_bf, enc0, bar);
    // final hidden lands at parity 0 (400 even)

    if (fuse) {
        // ---- decoder: ONE persistent launch, 512 blocks (2/CU, 8 waves/CU) ----
        k_dec_persist<<<512, 256, 0, stream>>>(
            emb, enc0, attn_W, attn_b, comb_W, comb_b,
            tier1 ? decWb : nullptr, dec_Wih, dec_Whh, dec_bih, dec_bhh,
            tier2 ? outWb : nullptr, out_W, out_b, target_t,
            h_f32, h_bf, c_bf, scores, pm, ps, tlog, lacc, bar2);
    } else {
        // ---- fallback: 100 sequential steps x 4 kernels ----
        for (int td = 0; td < 100; ++td) {
            const float* hi  = h_f32 + (td & 1) * 32768;
            const short* hib = h_bf  + (td & 1) * 32768;
            float* ho  = h_f32 + ((td + 1) & 1) * 32768;
            short* hob = h_bf  + ((td + 1) & 1) * 32768;
            k_attncomb<<<64, 256, 0, stream>>>(emb, hi, enc0, attn_W, attn_b,
                                               comb_W, comb_b, target_t, td, c_bf);
            k_gru1<<<32, 256, 0, stream>>>(c_bf, tier1 ? decWb : nullptr,
                                           dec_Wih, dec_Whh, dec_bih, dec_bhh,
                                           hi, hib, ho, hob);
            k_outloss<<<782, 256, 0, stream>>>(hob, tier2 ? outWb : nullptr, out_W,
                                               out_b, target_t + td * 64,
                                               pm, ps, tlog);
            k_lossred<<<64, 256, 0, stream>>>(pm, ps, tlog, lacc);
        }
    }

    k_final<<<1, 1, 0, stream>>>(lacc, (float*)d_out);
}

// Round 3
// 28273.315 us; speedup vs baseline: 2.0097x; 2.0097x over previous
//
#include <hip/hip_runtime.h>
#include <math.h>

// ---------------------------------------------------------------------------
// Seq2Seq forward. V=50000 E=H=512 Lin=400 Tout=100 B=64 Lmax=400.
// R8: fix grid-barrier cache poisoning. R7 evidence: rates (VALU/MFMA/HBM)
// halved when spinner count doubled -> the per-poll ACQUIRE load was emitting
// an L2/L1 invalidate every ~1us per spinner, keeping all 8 XCD L2s
// permanently invalidated (all phases then run at L3/MALL latency).
// gridbar v2: arrive = release fetch_add (wbL2, needed for visibility);
// poll = RELAXED fetch_add(0) (coherence-point RMW, NO cache maintenance,
// no stale-cache hang); exit = ONE acquire fence (leader inv covers the
// CU L1 + XCD L2 for the whole block). Decoder back to the proven
// 256-block R6 structure, keeping R7's phase-D prefetch-16.
// ---------------------------------------------------------------------------

typedef __attribute__((ext_vector_type(8))) short bh8;   // 8 x bf16 = 4 VGPR
typedef __attribute__((ext_vector_type(4))) float fv4;

__device__ __forceinline__ float b2f(short u) {
    union { unsigned int i; float f; } c;
    c.i = ((unsigned int)(unsigned short)u) << 16;
    return c.f;
}
// round-to-nearest-even f32 -> bf16 bits
__device__ __forceinline__ short f2b(float f) {
    union { float f; unsigned int u; } c;
    c.f = f;
    unsigned int r = (c.u + 0x7fffu + ((c.u >> 16) & 1u)) >> 16;
    return (short)r;
}
// load 8 consecutive f32, convert to bf16x8 fragment
__device__ __forceinline__ bh8 ld8(const float* __restrict__ p) {
    bh8 r;
    #pragma unroll
    for (int j = 0; j < 8; ++j) r[j] = f2b(p[j]);
    return r;
}
__device__ __forceinline__ float sigmf(float x) { return 1.f / (1.f + expf(-x)); }

__device__ __forceinline__ fv4 mfma16(bh8 a, bh8 b, fv4 c) {
    return __builtin_amdgcn_mfma_f32_16x16x32_bf16(a, b, c, 0, 0, 0);
}

// Grid barrier v2. Arrive: release add (writes back this XCD's dirty L2 so
// remote readers see our stores). Poll: relaxed fetch_add(0) -- executes at
// the coherence point (never served by a stale local cache line, so no hang)
// and emits NO invalidate (the R6/R7 poison). Exit: one acquire fence;
// leader's buffer_inv invalidates the per-CU L1 + per-XCD L2, covering all
// threads of this block (L1 is per-CU, L2 per-XCD).
__device__ __forceinline__ void gridbar(unsigned int* bar, unsigned int target) {
    __syncthreads();
    if (threadIdx.x == 0) {
        __hip_atomic_fetch_add(bar, 1u, __ATOMIC_RELEASE, __HIP_MEMORY_SCOPE_AGENT);
        while (__hip_atomic_fetch_add(bar, 0u, __ATOMIC_RELAXED,
                                      __HIP_MEMORY_SCOPE_AGENT) < target) {
            __builtin_amdgcn_s_sleep(16);   // ~1024 cy ~0.43us between polls
        }
        __builtin_amdgcn_fence(__ATOMIC_ACQUIRE, "agent");  // single inv
    }
    __syncthreads();
}

// f32 -> bf16 bulk convert (n multiple of 4; grid = n/1024 blocks)
__global__ __launch_bounds__(256) void k_cvt(
    const float* __restrict__ s, short* __restrict__ d, int n)
{
    const int i = (blockIdx.x * 256 + threadIdx.x) * 4;
    if (i + 3 < n) {
        fv4 v = *(const fv4*)(s + i);
        short4 o;
        o.x = f2b(v[0]); o.y = f2b(v[1]); o.z = f2b(v[2]); o.w = f2b(v[3]);
        *(short4*)(d + i) = o;
    }
}

// ---------------------------------------------------------------------------
// Persistent encoder: all 400 GRU steps in one launch. 32 blocks x 256 thr.
// (structure unchanged from R5; benefits from gridbar v2)
// ---------------------------------------------------------------------------
__global__ __launch_bounds__(256) void k_enc_persist(
    const float* __restrict__ emb, const int* __restrict__ input_t,
    const short* __restrict__ Wb,
    const float* __restrict__ Wih_f, const float* __restrict__ Whh_f,
    const float* __restrict__ bih, const float* __restrict__ bhh,
    float* __restrict__ h_f32, short* __restrict__ h_bf,
    float* __restrict__ enc0, unsigned int* __restrict__ bar)
{
    const int tid  = threadIdx.x;
    const int lane = tid & 63;
    const int wv   = tid >> 6;            // b-tile index 0..3
    const int n0   = blockIdx.x * 16;     // n-strip
    const int b0   = wv * 16;
    const int l15  = lane & 15;
    const int ko   = lane >> 4;
    const int koff = ko * 8;
    const int brow = b0 + l15;
    const int n    = n0 + l15;

    for (int i = blockIdx.x * 256 + tid; i < 64 * 512; i += 32 * 256) {
        h_f32[i] = 0.f; h_bf[i] = 0;
    }
    gridbar(bar, 32u);

    const bh8 *Wrb = nullptr, *Wzb = nullptr, *Wnb = nullptr;
    const bh8 *Urb = nullptr, *Uzb = nullptr, *Unb = nullptr;
    const float *Wrf = nullptr, *Wzf = nullptr, *Wnf = nullptr;
    const float *Urf = nullptr, *Uzf = nullptr, *Unf = nullptr;
    if (Wb) {
        Wrb = (const bh8*)(Wb + (long long)(n + 0)    * 512) + ko;
        Wzb = (const bh8*)(Wb + (long long)(n + 512)  * 512) + ko;
        Wnb = (const bh8*)(Wb + (long long)(n + 1024) * 512) + ko;
        Urb = (const bh8*)(Wb + (long long)(n + 1536) * 512) + ko;
        Uzb = (const bh8*)(Wb + (long long)(n + 2048) * 512) + ko;
        Unb = (const bh8*)(Wb + (long long)(n + 2560) * 512) + ko;
    } else {
        Wrf = Wih_f + (long long)(n + 0)    * 512 + koff;
        Wzf = Wih_f + (long long)(n + 512)  * 512 + koff;
        Wnf = Wih_f + (long long)(n + 1024) * 512 + koff;
        Urf = Whh_f + (long long)(n + 0)    * 512 + koff;
        Uzf = Whh_f + (long long)(n + 512)  * 512 + koff;
        Unf = Whh_f + (long long)(n + 1024) * 512 + koff;
    }
    const float bir = bih[n], biz = bih[n + 512], bin = bih[n + 1024];
    const float bhr = bhh[n], bhz = bhh[n + 512], bhn = bhh[n + 1024];

    for (int t = 0; t < 400; ++t) {
        const float* hi  = h_f32 + (t & 1) * 32768;
        const short* hib = h_bf  + (t & 1) * 32768;
        float* ho  = h_f32 + ((t + 1) & 1) * 32768;
        short* hob = h_bf  + ((t + 1) & 1) * 32768;

        const int tok = input_t[t * 64 + brow];
        const float* Ap = emb + (long long)tok * 512 + koff;
        const bh8*  Hp  = (const bh8*)(hib + (long long)brow * 512) + ko;

        fv4 air = {0.f, 0.f, 0.f, 0.f};
        fv4 aiz = air, ain = air, ahr = air, ahz = air, ahn = air;
        if (Wb) {
            #pragma unroll 4
            for (int kk = 0; kk < 16; ++kk) {
                const bh8 a = ld8(Ap + kk * 32);
                const bh8 h = Hp[kk * 4];
                air = mfma16(a, Wrb[kk * 4], air);
                aiz = mfma16(a, Wzb[kk * 4], aiz);
                ain = mfma16(a, Wnb[kk * 4], ain);
                ahr = mfma16(h, Urb[kk * 4], ahr);
                ahz = mfma16(h, Uzb[kk * 4], ahz);
                ahn = mfma16(h, Unb[kk * 4], ahn);
            }
        } else {
            #pragma unroll 4
            for (int kk = 0; kk < 16; ++kk) {
                const bh8 a = ld8(Ap + kk * 32);
                const bh8 h = Hp[kk * 4];
                air = mfma16(a, ld8(Wrf + kk * 32), air);
                aiz = mfma16(a, ld8(Wzf + kk * 32), aiz);
                ain = mfma16(a, ld8(Wnf + kk * 32), ain);
                ahr = mfma16(h, ld8(Urf + kk * 32), ahr);
                ahz = mfma16(h, ld8(Uzf + kk * 32), ahz);
                ahn = mfma16(h, ld8(Unf + kk * 32), ahn);
            }
        }
        #pragma unroll
        for (int r = 0; r < 4; ++r) {
            const int b = b0 + ko * 4 + r;
            const float rr = sigmf(air[r] + bir + ahr[r] + bhr);
            const float zz = sigmf(aiz[r] + biz + ahz[r] + bhz);
            const float nn = tanhf(ain[r] + bin + rr * (ahn[r] + bhn));
            const float hold = hi[b * 512 + n];
            const float hnew = (1.f - zz) * nn + zz * hold;
            ho[b * 512 + n] = hnew;
            hob[b * 512 + n] = f2b(hnew);
            if (t == 0) enc0[b * 512 + n] = hnew;
        }
        gridbar(bar, 32u * (t + 2));
    }
}

// ---------------------------------------------------------------------------
// Fused persistent decoder: 100 steps, one launch. 256 blocks x 256 threads
// (one per CU -> co-resident). Block (r = bid>>2, q = bid&3).
// Phase A: stage [x|h] in LDS; fold loss-red of step t-1 (q==0 blocks);
//          attention scores (q-th 100 rows of 400). gridbar.
// Phase B: softmax over scores row -> a0; combine GEMV (q-th 128 of 512)
//          -> c_bf. gridbar.
// Phase C: GRU step (blocks 0..31). gridbar.
// Phase D: out GEMM + online-LSE partials, 782 chunks over 256 blocks,
//          out_W panel prefetched into registers (16 loads in flight). gridbar.
// ---------------------------------------------------------------------------
struct SmAB { float sx[1024]; float red[256]; float red2[256]; };
struct SmD  { float sl[64][65]; };
union SMem { SmAB ab; SmD d; };

__device__ __forceinline__ void dec_lossred(
    const float* __restrict__ pm, const float* __restrict__ ps,
    const float* __restrict__ tlog, float* __restrict__ lacc,
    float* red, float* red2, int r, int tid)
{
    float m = -1e30f, s = 0.f;
    for (int i = tid; i < 782; i += 256) {
        const float m2 = pm[i * 64 + r];
        const float s2 = ps[i * 64 + r];
        if (m2 > m) { s = s * expf(m - m2) + s2; m = m2; }
        else        { s += s2 * expf(m2 - m); }
    }
    red[tid] = m; red2[tid] = s;
    __syncthreads();
    for (int st = 128; st > 0; st >>= 1) {
        if (tid < st) {
            const float m2 = red[tid + st], s2 = red2[tid + st];
            const float M = fmaxf(red[tid], m2);
            red2[tid] = red2[tid] * expf(red[tid] - M) + s2 * expf(m2 - M);
            red[tid] = M;
        }
        __syncthreads();
    }
    if (tid == 0) {
        const float logp = tlog[r] - (red[0] + logf(red2[0]));
        atomicAdd(lacc, -logp * (1.f / 64.f));
    }
    __syncthreads();
}

__global__ __launch_bounds__(256) void k_dec_persist(
    const float* __restrict__ emb, const float* __restrict__ enc0,
    const float* __restrict__ attn_W, const float* __restrict__ attn_b,
    const float* __restrict__ comb_W, const float* __restrict__ comb_b,
    const short* __restrict__ decWb,
    const float* __restrict__ dec_Wih, const float* __restrict__ dec_Whh,
    const float* __restrict__ dec_bih, const float* __restrict__ dec_bhh,
    const short* __restrict__ outWb, const float* __restrict__ outW,
    const float* __restrict__ outb, const int* __restrict__ target,
    float* __restrict__ h_f32, short* __restrict__ h_bf,
    short* __restrict__ c_bf, float* __restrict__ scores,
    float* __restrict__ pm, float* __restrict__ ps,
    float* __restrict__ tlog, float* __restrict__ lacc,
    unsigned int* __restrict__ bar2)
{
    __shared__ SMem sm;
    const int tid = threadIdx.x;
    const int bid = blockIdx.x;
    const int r   = bid >> 2;     // batch row 0..63
    const int q   = bid & 3;      // quarter
    unsigned int tgt = 0u;

    for (int t = 0; t < 100; ++t) {
        const float* hi  = h_f32 + (t & 1) * 32768;
        const short* hib = h_bf  + (t & 1) * 32768;
        float* ho  = h_f32 + ((t + 1) & 1) * 32768;
        short* hob = h_bf  + ((t + 1) & 1) * 32768;

        // ------------------ Phase A ------------------
        const int tok = (t == 0) ? 1 : target[(t - 1) * 64 + r];
        for (int k = tid; k < 512; k += 256) {
            sm.ab.sx[k]       = emb[(long long)tok * 512 + k];
            sm.ab.sx[512 + k] = hi[r * 512 + k];
        }
        if (q == 0 && t > 0)   // finish loss of step t-1 (disjoint LDS region)
            dec_lossred(pm, ps, tlog, lacc, sm.ab.red, sm.ab.red2, r, tid);
        __syncthreads();
        if (tid < 100) {
            const int nn = q * 100 + tid;
            const fv4* wrow = (const fv4*)(attn_W + (long long)nn * 1024);
            float s0 = 0.f, s1 = 0.f, s2 = 0.f, s3 = 0.f;
            for (int kc = 0; kc < 256; ++kc) {
                fv4 v = wrow[kc];
                s0 += v[0] * sm.ab.sx[kc * 4 + 0];
                s1 += v[1] * sm.ab.sx[kc * 4 + 1];
                s2 += v[2] * sm.ab.sx[kc * 4 + 2];
                s3 += v[3] * sm.ab.sx[kc * 4 + 3];
            }
            scores[r * 400 + nn] = (s0 + s1) + (s2 + s3) + attn_b[nn];
        }
        tgt += 256u; gridbar(bar2, tgt);

        // ------------------ Phase B ------------------
        {
            float m = -1e30f;
            for (int i = tid; i < 400; i += 256) m = fmaxf(m, scores[r * 400 + i]);
            sm.ab.red[tid] = m;
            __syncthreads();
            for (int st = 128; st > 0; st >>= 1) {
                if (tid < st) sm.ab.red[tid] = fmaxf(sm.ab.red[tid], sm.ab.red[tid + st]);
                __syncthreads();
            }
            m = sm.ab.red[0];
            __syncthreads();
            float ssum = 0.f;
            for (int i = tid; i < 400; i += 256) ssum += expf(scores[r * 400 + i] - m);
            sm.ab.red2[tid] = ssum;
            __syncthreads();
            for (int st = 128; st > 0; st >>= 1) {
                if (tid < st) sm.ab.red2[tid] += sm.ab.red2[tid + st];
                __syncthreads();
            }
            const float a0 = expf(scores[r * 400 + 0] - m) / sm.ab.red2[0];
            __syncthreads();
            for (int k = tid; k < 512; k += 256)
                sm.ab.sx[512 + k] = enc0[r * 512 + k] * a0;
            __syncthreads();
        }
        if (tid < 128) {
            const int j = q * 128 + tid;
            const fv4* wrow = (const fv4*)(comb_W + (long long)j * 1024);
            float s0 = 0.f, s1 = 0.f, s2 = 0.f, s3 = 0.f;
            for (int kc = 0; kc < 256; ++kc) {
                fv4 v = wrow[kc];
                s0 += v[0] * sm.ab.sx[kc * 4 + 0];
                s1 += v[1] * sm.ab.sx[kc * 4 + 1];
                s2 += v[2] * sm.ab.sx[kc * 4 + 2];
                s3 += v[3] * sm.ab.sx[kc * 4 + 3];
            }
            const float acc = (s0 + s1) + (s2 + s3) + comb_b[j];
            c_bf[r * 512 + j] = f2b(fmaxf(acc, 0.f));
        }
        tgt += 256u; gridbar(bar2, tgt);

        // ------------------ Phase C: GRU (blocks 0..31) ------------------
        if (bid < 32) {
            const int lane = tid & 63;
            const int w    = bid * 4 + (tid >> 6);
            const int b0g  = (w & 3) * 16;
            const int n0g  = (w >> 2) * 16;
            const int l15  = lane & 15;
            const int ko   = lane >> 4;
            const int koff = ko * 8;
            const int brow = b0g + l15;
            const int n    = n0g + l15;

            const bh8* Ap = (const bh8*)(c_bf + (long long)brow * 512) + ko;
            const bh8* Hp = (const bh8*)(hib + (long long)brow * 512) + ko;

            fv4 air = {0.f, 0.f, 0.f, 0.f};
            fv4 aiz = air, ain = air, ahr = air, ahz = air, ahn = air;
            if (decWb) {
                const bh8* Wr = (const bh8*)(decWb + (long long)(n + 0)    * 512) + ko;
                const bh8* Wz = (const bh8*)(decWb + (long long)(n + 512)  * 512) + ko;
                const bh8* Wn = (const bh8*)(decWb + (long long)(n + 1024) * 512) + ko;
                const bh8* Ur = (const bh8*)(decWb + (long long)(n + 1536) * 512) + ko;
                const bh8* Uz = (const bh8*)(decWb + (long long)(n + 2048) * 512) + ko;
                const bh8* Un = (const bh8*)(decWb + (long long)(n + 2560) * 512) + ko;
                #pragma unroll 4
                for (int kk = 0; kk < 16; ++kk) {
                    const bh8 a = Ap[kk * 4];
                    const bh8 h = Hp[kk * 4];
                    air = mfma16(a, Wr[kk * 4], air);
                    aiz = mfma16(a, Wz[kk * 4], aiz);
                    ain = mfma16(a, Wn[kk * 4], ain);
                    ahr = mfma16(h, Ur[kk * 4], ahr);
                    ahz = mfma16(h, Uz[kk * 4], ahz);
                    ahn = mfma16(h, Un[kk * 4], ahn);
                }
            } else {
                const float* Wr = dec_Wih + (long long)(n + 0)    * 512 + koff;
                const float* Wz = dec_Wih + (long long)(n + 512)  * 512 + koff;
                const float* Wn = dec_Wih + (long long)(n + 1024) * 512 + koff;
                const float* Ur = dec_Whh + (long long)(n + 0)    * 512 + koff;
                const float* Uz = dec_Whh + (long long)(n + 512)  * 512 + koff;
                const float* Un = dec_Whh + (long long)(n + 1024) * 512 + koff;
                #pragma unroll 4
                for (int kk = 0; kk < 16; ++kk) {
                    const bh8 a = Ap[kk * 4];
                    const bh8 h = Hp[kk * 4];
                    air = mfma16(a, ld8(Wr + kk * 32), air);
                    aiz = mfma16(a, ld8(Wz + kk * 32), aiz);
                    ain = mfma16(a, ld8(Wn + kk * 32), ain);
                    ahr = mfma16(h, ld8(Ur + kk * 32), ahr);
                    ahz = mfma16(h, ld8(Uz + kk * 32), ahz);
                    ahn = mfma16(h, ld8(Un + kk * 32), ahn);
                }
            }
            const float bir = dec_bih[n], biz = dec_bih[n + 512], bin = dec_bih[n + 1024];
            const float bhr = dec_bhh[n], bhz = dec_bhh[n + 512], bhn = dec_bhh[n + 1024];
            #pragma unroll
            for (int rr = 0; rr < 4; ++rr) {
                const int b = b0g + ko * 4 + rr;
                const float rg = sigmf(air[rr] + bir + ahr[rr] + bhr);
                const float zg = sigmf(aiz[rr] + biz + ahz[rr] + bhz);
                const float ng = tanhf(ain[rr] + bin + rg * (ahn[rr] + bhn));
                const float hold = hi[b * 512 + n];
                const float hnew = (1.f - zg) * ng + zg * hold;
                ho[b * 512 + n] = hnew;
                hob[b * 512 + n] = f2b(hnew);
            }
        }
        tgt += 256u; gridbar(bar2, tgt);

        // ------------------ Phase D: out GEMM + LSE partials ------------------
        for (int ch = bid; ch < 782; ch += 256) {
            const int lane = tid & 63;
            const int wl   = tid >> 6;
            const int base = ch * 64;
            const int n0c  = base + wl * 16;
            const int l15  = lane & 15;
            const int ko   = lane >> 4;
            const int v    = n0c + l15;
            const int vcl  = (v < 50000) ? v : 49999;
            const bh8* A0 = (const bh8*)(hob + (long long)(0  + l15) * 512) + ko;
            const bh8* A1 = (const bh8*)(hob + (long long)(16 + l15) * 512) + ko;
            const bh8* A2 = (const bh8*)(hob + (long long)(32 + l15) * 512) + ko;
            const bh8* A3 = (const bh8*)(hob + (long long)(48 + l15) * 512) + ko;

            // Prefetch the full out_W panel for this chunk: 16 independent
            // 16B loads in flight per wave.
            bh8 bb[16];
            if (outWb) {
                const bh8* Bp = (const bh8*)(outWb + (long long)vcl * 512) + ko;
                #pragma unroll
                for (int kk = 0; kk < 16; ++kk) bb[kk] = Bp[kk * 4];
            } else {
                const float* Bp = outW + (long long)vcl * 512 + ko * 8;
                #pragma unroll
                for (int kk = 0; kk < 16; ++kk) bb[kk] = ld8(Bp + kk * 32);
            }
            fv4 c0 = {0.f, 0.f, 0.f, 0.f};
            fv4 c1 = c0, c2 = c0, c3 = c0;
            #pragma unroll
            for (int kk = 0; kk < 16; ++kk) {
                c0 = mfma16(A0[kk * 4], bb[kk], c0);
                c1 = mfma16(A1[kk * 4], bb[kk], c1);
                c2 = mfma16(A2[kk * 4], bb[kk], c2);
                c3 = mfma16(A3[kk * 4], bb[kk], c3);
            }
            const float bv = outb[vcl];
            const int cc = wl * 16 + l15;
            const bool ok = (v < 50000);
            #pragma unroll
            for (int rr = 0; rr < 4; ++rr) {
                const int row = ko * 4 + rr;
                sm.d.sl[0  + row][cc] = ok ? (c0[rr] + bv) : -1e30f;
                sm.d.sl[16 + row][cc] = ok ? (c1[rr] + bv) : -1e30f;
                sm.d.sl[32 + row][cc] = ok ? (c2[rr] + bv) : -1e30f;
                sm.d.sl[48 + row][cc] = ok ? (c3[rr] + bv) : -1e30f;
            }
            __syncthreads();
            if (tid < 64) {
                const int b = tid;
                float m = -1e30f, s = 0.f;
                for (int cj = 0; cj < 64; ++cj) {
                    const float x = sm.d.sl[b][cj];
                    if (x > m) { s = s * expf(m - x) + 1.f; m = x; }
                    else       { s += expf(x - m); }
                }
                pm[ch * 64 + b] = m;
                ps[ch * 64 + b] = s;
                const int tg = target[t * 64 + b];
                const int rel = tg - base;
                if (rel >= 0 && rel < 64) tlog[b] = sm.d.sl[b][rel];
            }
            __syncthreads();
        }
        tgt += 256u; gridbar(bar2, tgt);
    }

    // finish loss of step 99
    if (q == 0)
        dec_lossred(pm, ps, tlog, lacc, sm.ab.red, sm.ab.red2, r, tid);
}

// ---------------------------------------------------------------------------
// Fallback decoder kernels (used only when workspace is too small to fuse).
// ---------------------------------------------------------------------------
__global__ __launch_bounds__(256) void k_gru1(
    const short* __restrict__ c_bf, const short* __restrict__ Wb,
    const float* __restrict__ Wih_f, const float* __restrict__ Whh_f,
    const float* __restrict__ bih, const float* __restrict__ bhh,
    const float* __restrict__ hi, const short* __restrict__ hib,
    float* __restrict__ ho, short* __restrict__ hob)
{
    const int tid  = threadIdx.x;
    const int lane = tid & 63;
    const int w    = blockIdx.x * 4 + (tid >> 6);
    const int b0   = (w & 3) * 16;
    const int n0   = (w >> 2) * 16;
    const int l15  = lane & 15;
    const int ko   = lane >> 4;
    const int koff = ko * 8;
    const int brow = b0 + l15;
    const int n    = n0 + l15;

    const bh8* Ap = (const bh8*)(c_bf + (long long)brow * 512) + ko;
    const bh8* Hp = (const bh8*)(hib + (long long)brow * 512) + ko;

    fv4 air = {0.f, 0.f, 0.f, 0.f};
    fv4 aiz = air, ain = air, ahr = air, ahz = air, ahn = air;
    if (Wb) {
        const bh8* Wr = (const bh8*)(Wb + (long long)(n + 0)    * 512) + ko;
        const bh8* Wz = (const bh8*)(Wb + (long long)(n + 512)  * 512) + ko;
        const bh8* Wn = (const bh8*)(Wb + (long long)(n + 1024) * 512) + ko;
        const bh8* Ur = (const bh8*)(Wb + (long long)(n + 1536) * 512) + ko;
        const bh8* Uz = (const bh8*)(Wb + (long long)(n + 2048) * 512) + ko;
        const bh8* Un = (const bh8*)(Wb + (long long)(n + 2560) * 512) + ko;
        #pragma unroll 4
        for (int kk = 0; kk < 16; ++kk) {
            const bh8 a = Ap[kk * 4];
            const bh8 h = Hp[kk * 4];
            air = mfma16(a, Wr[kk * 4], air);
            aiz = mfma16(a, Wz[kk * 4], aiz);
            ain = mfma16(a, Wn[kk * 4], ain);
            ahr = mfma16(h, Ur[kk * 4], ahr);
            ahz = mfma16(h, Uz[kk * 4], ahz);
            ahn = mfma16(h, Un[kk * 4], ahn);
        }
    } else {
        const float* Wr = Wih_f + (long long)(n + 0)    * 512 + koff;
        const float* Wz = Wih_f + (long long)(n + 512)  * 512 + koff;
        const float* Wn = Wih_f + (long long)(n + 1024) * 512 + koff;
        const float* Ur = Whh_f + (long long)(n + 0)    * 512 + koff;
        const float* Uz = Whh_f + (long long)(n + 512)  * 512 + koff;
        const float* Un = Whh_f + (long long)(n + 1024) * 512 + koff;
        #pragma unroll 4
        for (int kk = 0; kk < 16; ++kk) {
            const bh8 a = Ap[kk * 4];
            const bh8 h = Hp[kk * 4];
            air = mfma16(a, ld8(Wr + kk * 32), air);
            aiz = mfma16(a, ld8(Wz + kk * 32), aiz);
            ain = mfma16(a, ld8(Wn + kk * 32), ain);
            ahr = mfma16(h, ld8(Ur + kk * 32), ahr);
            ahz = mfma16(h, ld8(Uz + kk * 32), ahz);
            ahn = mfma16(h, ld8(Un + kk * 32), ahn);
        }
    }
    const float bir = bih[n], biz = bih[n + 512], bin = bih[n + 1024];
    const float bhr = bhh[n], bhz = bhh[n + 512], bhn = bhh[n + 1024];
    #pragma unroll
    for (int r = 0; r < 4; ++r) {
        const int b = b0 + ko * 4 + r;
        const float rr = sigmf(air[r] + bir + ahr[r] + bhr);
        const float zz = sigmf(aiz[r] + biz + ahz[r] + bhz);
        const float nn = tanhf(ain[r] + bin + rr * (ahn[r] + bhn));
        const float hold = hi[b * 512 + n];
        const float hnew = (1.f - zz) * nn + zz * hold;
        ho[b * 512 + n] = hnew;
        hob[b * 512 + n] = f2b(hnew);
    }
}

__global__ __launch_bounds__(256) void k_attncomb(
    const float* __restrict__ emb, const float* __restrict__ h_f32,
    const float* __restrict__ enc0,
    const float* __restrict__ attn_W, const float* __restrict__ attn_b,
    const float* __restrict__ comb_W, const float* __restrict__ comb_b,
    const int* __restrict__ target, int td, short* __restrict__ c_bf)
{
    __shared__ float sx[1024];
    __shared__ float sc[400];
    __shared__ float red[256];
    __shared__ float a0s;
    const int b = blockIdx.x;
    const int tid = threadIdx.x;
    const int tok = (td == 0) ? 1 : target[(td - 1) * 64 + b];
    for (int k = tid; k < 512; k += 256) {
        sx[k] = emb[(long long)tok * 512 + k];
        sx[512 + k] = h_f32[b * 512 + k];
    }
    __syncthreads();
    for (int nn = tid; nn < 400; nn += 256) {
        const fv4* wrow = (const fv4*)(attn_W + (long long)nn * 1024);
        float acc = 0.f;
        for (int kc = 0; kc < 256; ++kc) {
            fv4 v = wrow[kc];
            acc += v[0] * sx[kc * 4 + 0] + v[1] * sx[kc * 4 + 1]
                 + v[2] * sx[kc * 4 + 2] + v[3] * sx[kc * 4 + 3];
        }
        sc[nn] = acc + attn_b[nn];
    }
    __syncthreads();
    float m = -1e30f;
    for (int nn = tid; nn < 400; nn += 256) m = fmaxf(m, sc[nn]);
    red[tid] = m;
    __syncthreads();
    for (int s = 128; s > 0; s >>= 1) {
        if (tid < s) red[tid] = fmaxf(red[tid], red[tid + s]);
        __syncthreads();
    }
    m = red[0];
    __syncthreads();
    float ss = 0.f;
    for (int nn = tid; nn < 400; nn += 256) ss += expf(sc[nn] - m);
    red[tid] = ss;
    __syncthreads();
    for (int s = 128; s > 0; s >>= 1) {
        if (tid < s) red[tid] += red[tid + s];
        __syncthreads();
    }
    if (tid == 0) a0s = expf(sc[0] - m) / red[0];
    __syncthreads();
    const float a0b = a0s;
    for (int k = tid; k < 512; k += 256) sx[512 + k] = enc0[b * 512 + k] * a0b;
    __syncthreads();
    for (int j = tid; j < 512; j += 256) {
        const fv4* wrow = (const fv4*)(comb_W + (long long)j * 1024);
        float acc = 0.f;
        for (int kc = 0; kc < 256; ++kc) {
            fv4 v = wrow[kc];
            acc += v[0] * sx[kc * 4 + 0] + v[1] * sx[kc * 4 + 1]
                 + v[2] * sx[kc * 4 + 2] + v[3] * sx[kc * 4 + 3];
        }
        acc += comb_b[j];
        c_bf[b * 512 + j] = f2b(fmaxf(acc, 0.f));
    }
}

__global__ __launch_bounds__(256) void k_outloss(
    const short* __restrict__ h2bf,
    const short* __restrict__ outWb, const float* __restrict__ outW,
    const float* __restrict__ outb, const int* __restrict__ target,
    float* __restrict__ pm, float* __restrict__ ps, float* __restrict__ tlogit)
{
    __shared__ float sl[64][65];
    const int tid  = threadIdx.x;
    const int lane = tid & 63;
    const int wl   = tid >> 6;
    const int base = blockIdx.x * 64;
    const int n0   = base + wl * 16;
    const int l15  = lane & 15;
    const int ko   = lane >> 4;

    const int v    = n0 + l15;
    const int vcl  = (v < 50000) ? v : 49999;
    const bh8* A0 = (const bh8*)(h2bf + (long long)(0  + l15) * 512) + ko;
    const bh8* A1 = (const bh8*)(h2bf + (long long)(16 + l15) * 512) + ko;
    const bh8* A2 = (const bh8*)(h2bf + (long long)(32 + l15) * 512) + ko;
    const bh8* A3 = (const bh8*)(h2bf + (long long)(48 + l15) * 512) + ko;
    fv4 c0 = {0.f, 0.f, 0.f, 0.f};
    fv4 c1 = c0, c2 = c0, c3 = c0;
    if (outWb) {
        const bh8* Bp = (const bh8*)(outWb + (long long)vcl * 512) + ko;
        #pragma unroll 4
        for (int kk = 0; kk < 16; ++kk) {
            const bh8 bb = Bp[kk * 4];
            c0 = mfma16(A0[kk * 4], bb, c0);
            c1 = mfma16(A1[kk * 4], bb, c1);
            c2 = mfma16(A2[kk * 4], bb, c2);
            c3 = mfma16(A3[kk * 4], bb, c3);
        }
    } else {
        const float* Bp = outW + (long long)vcl * 512 + ko * 8;
        #pragma unroll 4
        for (int kk = 0; kk < 16; ++kk) {
            const bh8 bb = ld8(Bp + kk * 32);
            c0 = mfma16(A0[kk * 4], bb, c0);
            c1 = mfma16(A1[kk * 4], bb, c1);
            c2 = mfma16(A2[kk * 4], bb, c2);
            c3 = mfma16(A3[kk * 4], bb, c3);
        }
    }
    const float bv = outb[vcl];
    const int cc = wl * 16 + l15;
    const bool ok = (v < 50000);
    #pragma unroll
    for (int r = 0; r < 4; ++r) {
        const int row = ko * 4 + r;
        sl[0  + row][cc] = ok ? (c0[r] + bv) : -1e30f;
        sl[16 + row][cc] = ok ? (c1[r] + bv) : -1e30f;
        sl[32 + row][cc] = ok ? (c2[r] + bv) : -1e30f;
        sl[48 + row][cc] = ok ? (c3[r] + bv) : -1e30f;
    }
    __syncthreads();
    if (tid < 64) {
        const int b = tid;
        float m = -1e30f, s = 0.f;
        for (int c = 0; c < 64; ++c) {
            const float x = sl[b][c];
            if (x > m) { s = s * expf(m - x) + 1.f; m = x; }
            else       { s += expf(x - m); }
        }
        pm[blockIdx.x * 64 + b] = m;
        ps[blockIdx.x * 64 + b] = s;
        const int tg = target[b];
        const int rel = tg - base;
        if (rel >= 0 && rel < 64) tlogit[b] = sl[b][rel];
    }
}

__global__ __launch_bounds__(256) void k_lossred(
    const float* __restrict__ pm, const float* __restrict__ ps,
    const float* __restrict__ tlogit, float* __restrict__ loss_acc)
{
    __shared__ float rm[256], rs[256];
    const int b = blockIdx.x;
    const int tid = threadIdx.x;
    float m = -1e30f, s = 0.f;
    for (int i = tid; i < 782; i += 256) {
        const float m2 = pm[i * 64 + b];
        const float s2 = ps[i * 64 + b];
        if (m2 > m) { s = s * expf(m - m2) + s2; m = m2; }
        else        { s += s2 * expf(m2 - m); }
    }
    rm[tid] = m; rs[tid] = s;
    __syncthreads();
    for (int st = 128; st > 0; st >>= 1) {
        if (tid < st) {
            const float m2 = rm[tid + st], s2 = rs[tid + st];
            const float M = fmaxf(rm[tid], m2);
            rs[tid] = rs[tid] * expf(rm[tid] - M) + s2 * expf(m2 - M);
            rm[tid] = M;
        }
        __syncthreads();
    }
    if (tid == 0) {
        const float logp = tlogit[b] - (rm[0] + logf(rs[0]));
        atomicAdd(loss_acc, -logp * (1.f / 64.f));
    }
}

__global__ void k_init(float* h_f32_0, short* h_bf_0, float* loss_acc,
                       unsigned int* bar, unsigned int* bar2)
{
    const int i = blockIdx.x * 256 + threadIdx.x;
    if (i < 64 * 512) { h_f32_0[i] = 0.f; h_bf_0[i] = 0; }
    if (i == 0) { *loss_acc = 0.f; *bar = 0u; *bar2 = 0u; }
}

__global__ void k_final(const float* loss_acc, float* out)
{
    out[0] = *loss_acc;
}

extern "C" void kernel_launch(void* const* d_in, const int* in_sizes, int n_in,
                              void* d_out, int out_size, void* d_ws, size_t ws_size,
                              hipStream_t stream)
{
    const float* emb     = (const float*)d_in[0];
    const float* enc_Wih = (const float*)d_in[1];
    const float* enc_Whh = (const float*)d_in[2];
    const float* enc_bih = (const float*)d_in[3];
    const float* enc_bhh = (const float*)d_in[4];
    const float* attn_W  = (const float*)d_in[5];
    const float* attn_b  = (const float*)d_in[6];
    const float* comb_W  = (const float*)d_in[7];
    const float* comb_b  = (const float*)d_in[8];
    const float* dec_Wih = (const float*)d_in[9];
    const float* dec_Whh = (const float*)d_in[10];
    const float* dec_bih = (const float*)d_in[11];
    const float* dec_bhh = (const float*)d_in[12];
    const float* out_W   = (const float*)d_in[13];
    const float* out_b   = (const float*)d_in[14];
    const int*   input_t = (const int*)d_in[15];
    const int*   target_t= (const int*)d_in[16];

    char* ws = (char*)d_ws;
    float* h_f32  = (float*)(ws + 0);          // 2 x [64,512] f32
    float* enc0   = (float*)(ws + 262144);
    short* h_bf   = (short*)(ws + 393216);     // 2 x [64,512] bf16
    short* c_bf   = (short*)(ws + 524288);
    float* lacc   = (float*)(ws + 589824);
    unsigned int* bar  = (unsigned int*)(ws + 590080);
    unsigned int* bar2 = (unsigned int*)(ws + 590208);
    float* pm     = (float*)(ws + 590336);     // [782,64]
    float* ps     = (float*)(ws + 790528);
    float* tlog   = (float*)(ws + 990720);
    short* encWb  = (short*)(ws + 990976);     // 3072x512 bf16 = 3145728 B
    float* scores = (float*)(ws + 990976);     // [64,400] f32 aliases encWb
                                               // (encoder dead when decoder runs)
    short* decWb  = (short*)(ws + 4136704);    // 3145728 B
    short* outWb  = (short*)(ws + 7282432);    // 25600000 bf16 = 51200000 B

    const bool tier1 = ws_size >= 7282432;     // enc/dec weights bf16
    const bool tier2 = ws_size >= 58482432;    // + out_W bf16
    const bool fuse  = ws_size >= 1093376;     // scores region present

    k_init<<<128, 256, 0, stream>>>(h_f32, h_bf, lacc, bar, bar2);

    if (tier1) {
        k_cvt<<<768, 256, 0, stream>>>(enc_Wih, encWb, 786432);
        k_cvt<<<768, 256, 0, stream>>>(enc_Whh, encWb + 786432, 786432);
        k_cvt<<<768, 256, 0, stream>>>(dec_Wih, decWb, 786432);
        k_cvt<<<768, 256, 0, stream>>>(dec_Whh, decWb + 786432, 786432);
    }
    if (tier2) {
        k_cvt<<<25000, 256, 0, stream>>>(out_W, outWb, 25600000);
    }

    // ---- encoder: one persistent launch, 400 steps, grid barrier ----
    k_enc_persist<<<32, 256, 0, stream>>>(
        emb, input_t, tier1 ? encWb : nullptr, enc_Wih, enc_Whh,
        enc_bih, enc_bhh, h_f32, h_bf, enc0, bar);
    // final hidden lands at parity 0 (400 even)

    if (fuse) {
        // ---- decoder: ONE persistent launch, 256 blocks, gridbar v2 ----
        k_dec_persist<<<256, 256, 0, stream>>>(
            emb, enc0, attn_W, attn_b, comb_W, comb_b,
            tier1 ? decWb : nullptr, dec_Wih, dec_Whh, dec_bih, dec_bhh,
            tier2 ? outWb : nullptr, out_W, out_b, target_t,
            h_f32, h_bf, c_bf, scores, pm, ps, tlog, lacc, bar2);
    } else {
        // ---- fallback: 100 sequential steps x 4 kernels ----
        for (int td = 0; td < 100; ++td) {
            const float* hi  = h_f32 + (td & 1) * 32768;
            const short* hib = h_bf  + (td & 1) * 32768;
            float* ho  = h_f32 + ((td + 1) & 1) * 32768;
            short* hob = h_bf  + ((td + 1) & 1) * 32768;
            k_attncomb<<<64, 256, 0, stream>>>(emb, hi, enc0, attn_W, attn_b,
                                               comb_W, comb_b, target_t, td, c_bf);
            k_gru1<<<32, 256, 0, stream>>>(c_bf, tier1 ? decWb : nullptr,
                                           dec_Wih, dec_Whh, dec_bih, dec_bhh,
                                           hi, hib, ho, hob);
            k_outloss<<<782, 256, 0, stream>>>(hob, tier2 ? outWb : nullptr, out_W,
                                               out_b, target_t + td * 64,
                                               pm, ps, tlog);
            k_lossred<<<64, 256, 0, stream>>>(pm, ps, tlog, lacc);
        }
    }

    k_final<<<1, 1, 0, stream>>>(lacc, (float*)d_out);
}